// Round 18
// baseline (924.352 us; speedup 1.0000x reference)
//
#include <hip/hip_runtime.h>
#include <math.h>

#define B_  2
#define S_  1024
#define H_  4096
#define NH_ 32
#define HD_ 128
#define I_  11008
#define R_  2048   // B*S tokens

typedef __attribute__((ext_vector_type(4))) int i32x4;
typedef __attribute__((ext_vector_type(4))) float f32x4;
typedef __attribute__((ext_vector_type(8))) short bf16x8;

// Tiled int8 layout (v1, validated): for matrix [Rows][K], nk = K/64;
// tile (rb, kt) is 8192 B at ((rb*nk + kt)<<13), internally
// [kgrp 0..3][row 0..127][16B]  (kgrp = (k%64)/16).
//
// r14 LESSON: kernels with hand-counted s_waitcnt vmcnt(N) must never spill —
// scratch buffer ops count toward vmcnt. Keep launch_bounds at the no-spill
// occupancy ((256,2) for the dual-acc GEMMs; 3-acc QKV would spill — don't).
// r7 LESSON: global_load_lds global src is PER-LANE; LDS dest is wave-uniform.

// ---------------------------------------------------------------------------
__device__ __forceinline__ void gload_lds16(const void* g, void* l) {
    __builtin_amdgcn_global_load_lds(
        (const __attribute__((address_space(1))) unsigned int*)g,
        (__attribute__((address_space(3))) unsigned int*)l, 16, 0, 0);
}

__device__ __forceinline__ unsigned short f2bf(float f) {
    unsigned int u = __float_as_uint(f);
    u += 0x7fffu + ((u >> 16) & 1u);   // RNE
    return (unsigned short)(u >> 16);
}

// ---------------------------------------------------------------------------
// Pack one W (int32 [N][K]) into tiled-i8. Grid: (K/64, N/128).
__global__ __launch_bounds__(256)
void packW_k(const int* __restrict__ W, signed char* __restrict__ out, const int K)
{
    const int kt = blockIdx.x, cb = blockIdx.y, nk = gridDim.x;
    const int t = threadIdx.x;
    int* otile = (int*)(out + ((long)(cb * nk + kt) << 13));
#pragma unroll
    for (int i = 0; i < 8; ++i) {
        const int o = i * 256 + t;                 // int32 index in tile
        const int g = o >> 9, r = (o >> 2) & 127, jj = o & 3;
        const int4 w4 = *(const int4*)(W + (long)(cb * 128 + r) * K + kt * 64 + g * 16 + jj * 4);
        otile[o] = (w4.x & 255) | ((w4.y & 255) << 8) | ((w4.z & 255) << 16) | (w4.w << 24);
    }
}

// ---------------------------------------------------------------------------
// RoPE trig table: ctab[s*64+i] = (cos, sin) of s * 10000^(-2i/128).
// Same powf/sincosf op sequence rope_k used -> bit-identical values.
__global__ __launch_bounds__(256)
void ropetab_k(float2* __restrict__ ctab)
{
    const int idx = blockIdx.x * 256 + threadIdx.x;   // 65536 entries
    const int s = idx >> 6, i = idx & 63;
    const float inv = powf(10000.f, -(float)(2 * i) * (1.f / 128.f));
    const float f = (float)s * inv;
    float sn, c;
    sincosf(f, &sn, &c);
    ctab[idx] = make_float2(c, sn);
}

// ---------------------------------------------------------------------------
// RMSNorm + int8 quant (scale folded into w). Output in tiled-i8 (nk=64).
__global__ __launch_bounds__(256)
void rmsnorm_quant_k(const float* __restrict__ x, const float* __restrict__ w,
                     signed char* __restrict__ out)
{
    __shared__ float red[4];
    const int tid = threadIdx.x;
    const long row = blockIdx.x;
    const float4* xr = (const float4*)(x + row * H_);
    float4 xv[4];
    float ss = 0.f;
#pragma unroll
    for (int i = 0; i < 4; ++i) {
        xv[i] = xr[tid + i * 256];
        ss += xv[i].x * xv[i].x + xv[i].y * xv[i].y
            + xv[i].z * xv[i].z + xv[i].w * xv[i].w;
    }
#pragma unroll
    for (int off = 32; off; off >>= 1) ss += __shfl_xor(ss, off);
    if ((tid & 63) == 0) red[tid >> 6] = ss;
    __syncthreads();
    const float tot = red[0] + red[1] + red[2] + red[3];
    const float sc = 1.f / sqrtf(tot * (1.f / (float)H_) + 1e-6f);
    const float4* wr = (const float4*)w;
    int* ob = (int*)out;
    const long rb = row >> 7;
    const int rr = (int)(row & 127);
#pragma unroll
    for (int i = 0; i < 4; ++i) {
        const float4 wv = wr[tid + i * 256];
        const int b0 = (int)fminf(fmaxf(rintf(xv[i].x * sc * wv.x), -128.f), 127.f);
        const int b1 = (int)fminf(fmaxf(rintf(xv[i].y * sc * wv.y), -128.f), 127.f);
        const int b2 = (int)fminf(fmaxf(rintf(xv[i].z * sc * wv.z), -128.f), 127.f);
        const int b3 = (int)fminf(fmaxf(rintf(xv[i].w * sc * wv.w), -128.f), 127.f);
        const int packed = (b0 & 255) | ((b1 & 255) << 8) | ((b2 & 255) << 16) | (b3 << 24);
        const int j4 = tid + i * 256;              // int32 group within row
        const long a32 = ((rb * 64 + (j4 >> 4)) << 11) + (((j4 >> 2) & 3) << 9)
                       + (rr << 2) + (j4 & 3);
        ob[a32] = packed;
    }
}

// ---------------------------------------------------------------------------
// int8 GEMM (round-8 validated): BK=128 double-step, depth-2 ring, counted
// vmcnt(8), 64KB LDS -> 2 blocks/CU. Wave-out 64x64 (acc[4][4]).
__global__ __launch_bounds__(256, 2)
void gemm_i8t(const signed char* __restrict__ A8, const signed char* __restrict__ W8,
              const float* __restrict__ scale_ptr, const float* __restrict__ bias,
              const float* __restrict__ residual, float* __restrict__ C,
              const int N, const int K, const int gx)
{
    __shared__ __align__(16) signed char lsA[2][16384];
    __shared__ __align__(16) signed char lsB[2][16384];

    int bid = blockIdx.x;
    {   // bijective XCD chunked remap (m204)
        const int nwg = gridDim.x;
        const int q = nwg >> 3, r = nwg & 7;
        const int xcd = bid & 7, idx = bid >> 3;
        bid = (xcd < r) ? (xcd * (q + 1) + idx)
                        : (r * (q + 1) + (xcd - r) * q + idx);
    }
    const int bx = bid % gx, by = bid / gx;

    const int tid  = threadIdx.x;
    const int lane = tid & 63, wid = tid >> 6;
    const int bm = bx << 7, bn = by << 7;
    const int wm = (wid >> 1) << 6, wn = (wid & 1) << 6;

    i32x4 acc[4][4];
#pragma unroll
    for (int m = 0; m < 4; ++m)
#pragma unroll
        for (int n = 0; n < 4; ++n) acc[m][n] = (i32x4){0, 0, 0, 0};

    const int nk  = K >> 6;
    const int nk2 = K >> 7;
    const signed char* abase = A8 + ((long)bx * nk << 13);
    const signed char* bbase = W8 + ((long)by * nk << 13);
    const int sgg = wid * 4096 + lane * 16;        // GLOBAL src: per-lane
    const int sgl = wid * 4096;                    // LDS dest: wave-uniform

#pragma unroll
    for (int c = 0; c < 4; ++c) {
        gload_lds16(abase + sgg + c * 1024, lsA[0] + sgl + c * 1024);
        gload_lds16(bbase + sgg + c * 1024, lsB[0] + sgl + c * 1024);
    }

    for (int kt = 0; kt < nk2; ++kt) {
        const int cur = kt & 1, nxt = cur ^ 1;
        if (kt + 1 < nk2) {
            const signed char* at = abase + ((long)(kt + 1) << 14);
            const signed char* bt = bbase + ((long)(kt + 1) << 14);
#pragma unroll
            for (int c = 0; c < 4; ++c) {
                gload_lds16(at + sgg + c * 1024, lsA[nxt] + sgl + c * 1024);
                gload_lds16(bt + sgg + c * 1024, lsB[nxt] + sgl + c * 1024);
            }
            asm volatile("s_waitcnt vmcnt(8)" ::: "memory");
        } else {
            asm volatile("s_waitcnt vmcnt(0)" ::: "memory");
        }
        __builtin_amdgcn_s_barrier();

        const int kg = (lane >> 4) * 2048, fr = (lane & 15) * 16;
#pragma unroll
        for (int s = 0; s < 2; ++s) {
            const int off = s * 8192;
            i32x4 af[4], bf[4];
#pragma unroll
            for (int m = 0; m < 4; ++m)
                af[m] = *(const i32x4*)(lsA[cur] + off + kg + wm * 16 + m * 256 + fr);
#pragma unroll
            for (int n = 0; n < 4; ++n)
                bf[n] = *(const i32x4*)(lsB[cur] + off + kg + wn * 16 + n * 256 + fr);
            __builtin_amdgcn_s_setprio(1);
#pragma unroll
            for (int m = 0; m < 4; ++m)
#pragma unroll
                for (int n = 0; n < 4; ++n)
                    acc[m][n] = __builtin_amdgcn_mfma_i32_16x16x64_i8(af[m], bf[n], acc[m][n], 0, 0, 0);
            __builtin_amdgcn_s_setprio(0);
        }
        __builtin_amdgcn_s_barrier();
    }

    const float s = *scale_ptr;
    const int rq = (lane >> 4) * 4, fc = lane & 15;
#pragma unroll
    for (int m = 0; m < 4; ++m) {
#pragma unroll
        for (int n = 0; n < 4; ++n) {
            const int col = bn + wn + n * 16 + fc;
            const float bcol = bias[col];
#pragma unroll
            for (int r = 0; r < 4; ++r) {
                const int row = bm + wm + m * 16 + rq + r;
                float v = (float)acc[m][n][r] * s + bcol;
                if (residual) v += residual[(long)row * N + col];
                C[(long)row * N + col] = v;
            }
        }
    }
}

// ---------------------------------------------------------------------------
// Dual-accumulator shared-A GEMM skeleton (gemm_gu pattern, r11 validated):
// one block stages A once and computes two 128x128 output tiles from two
// weight operands. 48KB LDS ring, counted vmcnt(6), (256,2) no-spill.
// EPI 0 (gemm_gu): silu(g)*u -> quant -> AQ8 tiled-i8.
// EPI 1 (gemm_kv): K fp32 (pre-rope) + V bf16.
template<int EPI>
__global__ __launch_bounds__(256, 2)
void gemm_dual(const signed char* __restrict__ A8, const signed char* __restrict__ G8,
               const signed char* __restrict__ U8,
               const float* __restrict__ s1_p, const float* __restrict__ b1,
               const float* __restrict__ s2_p, const float* __restrict__ b2,
               const float* __restrict__ qscale, signed char* __restrict__ out8,
               float* __restrict__ Cf, unsigned short* __restrict__ Cbf,
               const int N, const int K, const int gx)
{
    __shared__ __align__(16) signed char lsA[2][8192];
    __shared__ __align__(16) signed char lsG[2][8192];
    __shared__ __align__(16) signed char lsU[2][8192];

    int bid = blockIdx.x;
    {   // bijective XCD chunked remap
        const int nwg = gridDim.x;
        const int q = nwg >> 3, r = nwg & 7;
        const int xcd = bid & 7, idx = bid >> 3;
        bid = (xcd < r) ? (xcd * (q + 1) + idx)
                        : (r * (q + 1) + (xcd - r) * q + idx);
    }
    const int bx = bid % gx, by = bid / gx;
    const int tid = threadIdx.x, lane = tid & 63, wid = tid >> 6;
    const int bm = bx << 7, bn = by << 7;
    const int wm = (wid >> 1) << 6, wn = (wid & 1) << 6;

    i32x4 ag[4][4], au[4][4];
#pragma unroll
    for (int m = 0; m < 4; ++m)
#pragma unroll
        for (int n = 0; n < 4; ++n) {
            ag[m][n] = (i32x4){0, 0, 0, 0};
            au[m][n] = (i32x4){0, 0, 0, 0};
        }

    const int nk = K >> 6;
    const signed char* abase = A8 + ((long)bx * nk << 13);
    const signed char* gbase = G8 + ((long)by * nk << 13);
    const signed char* ubase = U8 + ((long)by * nk << 13);
    const int sgg = wid * 2048 + lane * 16;        // GLOBAL src: per-lane
    const int sgl = wid * 2048;                    // LDS dest: wave-uniform

#pragma unroll
    for (int c = 0; c < 2; ++c) {
        gload_lds16(abase + sgg + c * 1024, lsA[0] + sgl + c * 1024);
        gload_lds16(gbase + sgg + c * 1024, lsG[0] + sgl + c * 1024);
        gload_lds16(ubase + sgg + c * 1024, lsU[0] + sgl + c * 1024);
    }

    for (int kt = 0; kt < nk; ++kt) {
        const int cur = kt & 1, nxt = cur ^ 1;
        if (kt + 1 < nk) {
            const signed char* at = abase + ((long)(kt + 1) << 13);
            const signed char* gt = gbase + ((long)(kt + 1) << 13);
            const signed char* ut = ubase + ((long)(kt + 1) << 13);
#pragma unroll
            for (int c = 0; c < 2; ++c) {
                gload_lds16(at + sgg + c * 1024, lsA[nxt] + sgl + c * 1024);
                gload_lds16(gt + sgg + c * 1024, lsG[nxt] + sgl + c * 1024);
                gload_lds16(ut + sgg + c * 1024, lsU[nxt] + sgl + c * 1024);
            }
            asm volatile("s_waitcnt vmcnt(6)" ::: "memory");   // drain step kt's 6
        } else {
            asm volatile("s_waitcnt vmcnt(0)" ::: "memory");
        }
        __builtin_amdgcn_s_barrier();              // step kt visible

        const int kg = (lane >> 4) * 2048, fr = (lane & 15) * 16;
        i32x4 af[4], gf[4], uf[4];
#pragma unroll
        for (int m = 0; m < 4; ++m)
            af[m] = *(const i32x4*)(lsA[cur] + kg + wm * 16 + m * 256 + fr);
#pragma unroll
        for (int n = 0; n < 4; ++n) {
            gf[n] = *(const i32x4*)(lsG[cur] + kg + wn * 16 + n * 256 + fr);
            uf[n] = *(const i32x4*)(lsU[cur] + kg + wn * 16 + n * 256 + fr);
        }
        __builtin_amdgcn_s_setprio(1);
#pragma unroll
        for (int m = 0; m < 4; ++m)
#pragma unroll
            for (int n = 0; n < 4; ++n) {
                ag[m][n] = __builtin_amdgcn_mfma_i32_16x16x64_i8(af[m], gf[n], ag[m][n], 0, 0, 0);
                au[m][n] = __builtin_amdgcn_mfma_i32_16x16x64_i8(af[m], uf[n], au[m][n], 0, 0, 0);
            }
        __builtin_amdgcn_s_setprio(0);
        __builtin_amdgcn_s_barrier();              // buf[cur] free
    }

    const float s1 = *s1_p, s2 = *s2_p;
    const int rq = (lane >> 4) * 4, fc = lane & 15;
    if (EPI == 0) {
        const float dinv = 1.f / qscale[0];
        const int nko = N >> 6;
#pragma unroll
        for (int m = 0; m < 4; ++m) {
#pragma unroll
            for (int n = 0; n < 4; ++n) {
                const int col = bn + wn + n * 16 + fc;
                const float bgc = b1[col], buc = b2[col];
                const int ktc = col >> 6, kgc = (col >> 4) & 3, jc = col & 15;
#pragma unroll
                for (int r = 0; r < 4; ++r) {
                    const int row = bm + wm + m * 16 + rq + r;
                    const float g = (float)ag[m][n][r] * s1 + bgc;
                    const float u = (float)au[m][n][r] * s2 + buc;
                    const float a = g / (1.f + __expf(-g)) * u;
                    const float qv = fminf(fmaxf(rintf(a * dinv), -128.f), 127.f);
                    const long addr = (((long)(row >> 7) * nko + ktc) << 13)
                                    + (kgc << 11) + ((row & 127) << 4) + jc;
                    out8[addr] = (signed char)(int)qv;
                }
            }
        }
    } else {
        // EPI 1: G-side -> K fp32 (rope consumes fp32), U-side -> V bf16
#pragma unroll
        for (int m = 0; m < 4; ++m) {
#pragma unroll
            for (int n = 0; n < 4; ++n) {
                const int col = bn + wn + n * 16 + fc;
                const float bkc = b1[col], bvc = b2[col];
#pragma unroll
                for (int r = 0; r < 4; ++r) {
                    const int row = bm + wm + m * 16 + rq + r;
                    Cf[(long)row * N + col]  = (float)ag[m][n][r] * s1 + bkc;
                    Cbf[(long)row * N + col] = f2bf((float)au[m][n][r] * s2 + bvc);
                }
            }
        }
    }
}

// ---------------------------------------------------------------------------
// RoPE: Q in-place fp32; K read fp32 -> roped -> written bf16.
// cos/sin from precomputed table (bit-identical values, no transcendentals).
__global__ __launch_bounds__(256)
void rope_k(float* __restrict__ q, const float* __restrict__ kin,
            unsigned short* __restrict__ kbf, const float2* __restrict__ ctab)
{
    const int row = blockIdx.x;            // token index b*S+s
    const int s = row & (S_ - 1);
    float* qr = q + (long)row * H_;
    const float* kr = kin + (long)row * H_;
    unsigned short* ko = kbf + (long)row * H_;
    const float2* ct = ctab + (s << 6);
    for (int t = threadIdx.x; t < NH_ * 64; t += 256) {
        const int nh = t >> 6, i = t & 63;
        const float2 cs = ct[i];
        const float c = cs.x, sn = cs.y;
        const int base = nh * 128 + i;
        const float q0 = qr[base], q1 = qr[base + 64];
        qr[base]      = q0 * c - q1 * sn;
        qr[base + 64] = q1 * c + q0 * sn;
        const float k0 = kr[base], k1 = kr[base + 64];
        ko[base]      = f2bf(k0 * c - k1 * sn);
        ko[base + 64] = f2bf(k1 * c + k0 * sn);
    }
}

// ---------------------------------------------------------------------------
// Flash attention, bf16 MFMA; K/V arrive pre-converted bf16.
__global__ __launch_bounds__(256, 3)
void attn_mfma_k(const float* __restrict__ q, const unsigned short* __restrict__ kbf,
                 const unsigned short* __restrict__ vbf, signed char* __restrict__ out8,
                 const float* __restrict__ osc)
{
    __shared__ __align__(16) char lsK[8192];        // [32 krow][128 d] bf16, XOR swizzle
    __shared__ __align__(16) char lsV[10240];       // V^T [128 d][40 pitch] bf16
    __shared__ __align__(16) char lsP[4][1024];     // per-wave P [16][32] bf16, XOR swizzle

    const int tid = threadIdx.x, lane = tid & 63, wid = tid >> 6;
    const int bid = blockIdx.x;
    const int qt = 15 - (bid >> 6);                 // reversed: long blocks first
    const int bh = bid & 63;
    const int b = bh >> 5, h = bh & 31;
    const int q0 = qt * 64;
    const int qw = q0 + wid * 16;                   // this wave's first q row

    const float* qbase = q + (long)(b * S_) * H_ + (long)h * HD_;
    const unsigned short* kbase = kbf + (long)(b * S_) * H_ + (long)h * HD_;
    const unsigned short* vbase = vbf + (long)(b * S_) * H_ + (long)h * HD_;

    const int frow = lane & 15, fgrp = lane >> 4;
    const float sc = 0.08838834764831845f;          // 1/sqrt(128), folded into Q

    bf16x8 qf[4];
    {
        const float* qr = qbase + (long)(qw + frow) * H_;
#pragma unroll
        for (int c = 0; c < 4; ++c) {
            const float4 a = *(const float4*)(qr + c * 32 + fgrp * 8);
            const float4 bq = *(const float4*)(qr + c * 32 + fgrp * 8 + 4);
            bf16x8 t;
            t[0] = (short)f2bf(a.x * sc);  t[1] = (short)f2bf(a.y * sc);
            t[2] = (short)f2bf(a.z * sc);  t[3] = (short)f2bf(a.w * sc);
            t[4] = (short)f2bf(bq.x * sc); t[5] = (short)f2bf(bq.y * sc);
            t[6] = (short)f2bf(bq.z * sc); t[7] = (short)f2bf(bq.w * sc);
            qf[c] = t;
        }
    }

    f32x4 oacc[8];
#pragma unroll
    for (int n2 = 0; n2 < 8; ++n2) oacc[n2] = (f32x4){0.f, 0.f, 0.f, 0.f};
    float mr[4] = {-1e30f, -1e30f, -1e30f, -1e30f};
    float lr[4] = {0.f, 0.f, 0.f, 0.f};

    const int nt = (q0 >> 5) + 2;
    for (int kt = 0; kt < nt; ++kt) {
        if (kt) __syncthreads();
        {
            const unsigned short* kg = kbase + (long)(kt * 32) * H_;
            const unsigned short* vg = vbase + (long)(kt * 32) * H_;
#pragma unroll
            for (int i = 0; i < 2; ++i) {
                const int lin = i * 256 + tid;      // 512 units of 8 bf16
                const int kr = lin >> 4;            // 0..31
                const int d8 = (lin & 15) * 8;      // 0..120
                const bf16x8 kv = *(const bf16x8*)(kg + (long)kr * H_ + d8);
                *(bf16x8*)(lsK + kr * 256 + ((d8 * 2) ^ ((kr & 7) << 4))) = kv;
                const bf16x8 vv = *(const bf16x8*)(vg + (long)kr * H_ + d8);
#pragma unroll
                for (int e = 0; e < 8; ++e)
                    *(unsigned short*)(lsV + (d8 + e) * 80 + kr * 2) = (unsigned short)vv[e];
            }
        }
        __syncthreads();

        if (kt * 32 <= qw + 15) {
            f32x4 s0 = (f32x4){0.f, 0.f, 0.f, 0.f};
            f32x4 s1 = (f32x4){0.f, 0.f, 0.f, 0.f};
            const int swz = (frow & 7) << 4;
#pragma unroll
            for (int c = 0; c < 4; ++c) {
                const int dby = c * 64 + fgrp * 16;
                const bf16x8 kfA = *(const bf16x8*)(lsK + frow * 256 + (dby ^ swz));
                const bf16x8 kfB = *(const bf16x8*)(lsK + (frow + 16) * 256 + (dby ^ swz));
                s0 = __builtin_amdgcn_mfma_f32_16x16x32_bf16(qf[c], kfA, s0, 0, 0, 0);
                s1 = __builtin_amdgcn_mfma_f32_16x16x32_bf16(qf[c], kfB, s1, 0, 0, 0);
            }

            const int colg0 = kt * 32 + frow;
            float cf[4];
#pragma unroll
            for (int r = 0; r < 4; ++r) {
                const int rowg = qw + fgrp * 4 + r;
                const float a0 = (colg0 <= rowg) ? s0[r] : -1e30f;
                const float a1 = (colg0 + 16 <= rowg) ? s1[r] : -1e30f;
                float mx = fmaxf(a0, a1);
#pragma unroll
                for (int off2 = 1; off2 < 16; off2 <<= 1) mx = fmaxf(mx, __shfl_xor(mx, off2));
                const float mnew = fmaxf(mr[r], mx);
                cf[r] = __expf(mr[r] - mnew);
                mr[r] = mnew;
                const float p0 = __expf(a0 - mnew);
                const float p1 = __expf(a1 - mnew);
                float sm = p0 + p1;
#pragma unroll
                for (int off2 = 1; off2 < 16; off2 <<= 1) sm += __shfl_xor(sm, off2);
                lr[r] = lr[r] * cf[r] + sm;
                const int row = fgrp * 4 + r;
                const int psw = (row & 3) << 4;
                *(unsigned short*)(lsP[wid] + row * 64 + ((frow * 2) ^ psw)) = f2bf(p0);
                *(unsigned short*)(lsP[wid] + row * 64 + (((16 + frow) * 2) ^ psw)) = f2bf(p1);
            }
#pragma unroll
            for (int n2 = 0; n2 < 8; ++n2) {
#pragma unroll
                for (int r = 0; r < 4; ++r) oacc[n2][r] *= cf[r];
            }
            const bf16x8 pf = *(const bf16x8*)(lsP[wid] + frow * 64 + ((fgrp * 16) ^ ((frow & 3) << 4)));
#pragma unroll
            for (int n2 = 0; n2 < 8; ++n2) {
                const bf16x8 vf = *(const bf16x8*)(lsV + (n2 * 16 + frow) * 80 + fgrp * 16);
                oacc[n2] = __builtin_amdgcn_mfma_f32_16x16x32_bf16(pf, vf, oacc[n2], 0, 0, 0);
            }
        }
    }

    // epilogue: o = oacc/l, q8 = clip(rint(o/osc)) -> tiled-i8 (nk = 64)
    const float oinv = 1.f / osc[0];
    float inv[4];
#pragma unroll
    for (int r = 0; r < 4; ++r) inv[r] = 1.f / lr[r];
#pragma unroll
    for (int n2 = 0; n2 < 8; ++n2) {
        const int kk = h * 128 + n2 * 16 + frow;
        const int ktc = kk >> 6, kgc = (kk >> 4) & 3, jc = kk & 15;
#pragma unroll
        for (int r = 0; r < 4; ++r) {
            const int rowt = b * S_ + qw + fgrp * 4 + r;
            const float ov = oacc[n2][r] * inv[r];
            const float qv = fminf(fmaxf(rintf(ov * oinv), -128.f), 127.f);
            const long addr = (((long)(rowt >> 7) * 64 + ktc) << 13)
                            + (kgc << 11) + ((rowt & 127) << 4) + jc;
            out8[addr] = (signed char)(int)qv;
        }
    }
}

// ---------------------------------------------------------------------------
extern "C" void kernel_launch(void* const* d_in, const int* in_sizes, int n_in,
                              void* d_out, int out_size, void* d_ws, size_t ws_size,
                              hipStream_t stream)
{
    const float* hidden = (const float*)d_in[0];
    const float* ln1 = (const float*)d_in[1];
    const float* ln2 = (const float*)d_in[2];
    const int* Wq = (const int*)d_in[3];
    const int* Wk = (const int*)d_in[4];
    const int* Wv = (const int*)d_in[5];
    const int* Wo = (const int*)d_in[6];
    const int* Wg = (const int*)d_in[7];
    const int* Wu = (const int*)d_in[8];
    const int* Wd = (const int*)d_in[9];
    const float* bq = (const float*)d_in[10];
    const float* bk = (const float*)d_in[11];
    const float* bv = (const float*)d_in[12];
    const float* bo = (const float*)d_in[13];
    const float* bg = (const float*)d_in[14];
    const float* bu = (const float*)d_in[15];
    const float* bd = (const float*)d_in[16];
    const float* sq = (const float*)d_in[17];
    const float* sk = (const float*)d_in[18];
    const float* sv = (const float*)d_in[19];
    const float* so = (const float*)d_in[20];
    const float* sg = (const float*)d_in[21];
    const float* su = (const float*)d_in[22];
    const float* sd = (const float*)d_in[23];
    const float* o_sc = (const float*)d_in[24];
    const float* d_sc = (const float*)d_in[25];

    // workspace layout (MiB offsets, peak 230 MiB):
    //  [0,8)     HQ8 tiled i8 (hq / oq / hq2, sequential reuse)
    //  [8,30)    AQ8 tiled i8 (2048 x 11008)
    //  [30,74)   WPa: Wq -> Wv -> Wg packed (44 MiB)
    //  [74,106)  Qb fp32 -> (post-attn) Hb
    //  [106,138) Kb fp32 (dead after rope)
    //  [138,154) Vbf bf16 ; [154,170) Kbf bf16   (dead after attn)
    //  [170,186) WPb: Wk -> Wo packed (16 MiB)
    //  [186,229) WPu: Wu packed (43 MiB)
    //  [106,149) WPd: Wd packed (43 MiB, over dead Kb/Vbf, packed after attn)
    //  [229,229.5) ctab: rope trig table (512 KB)
    char* ws = (char*)d_ws;
    signed char* HQ8 = (signed char*)ws;
    signed char* AQ8 = (signed char*)(ws + ((size_t)8 << 20));
    signed char* WPa = (signed char*)(ws + ((size_t)30 << 20));
    float* Qb = (float*)(ws + ((size_t)74 << 20));
    float* Kb = (float*)(ws + ((size_t)106 << 20));
    unsigned short* Vbf = (unsigned short*)(ws + ((size_t)138 << 20));
    unsigned short* Kbf = (unsigned short*)(ws + ((size_t)154 << 20));
    signed char* WPb = (signed char*)(ws + ((size_t)170 << 20));
    signed char* WPu = (signed char*)(ws + ((size_t)186 << 20));
    signed char* WPd = (signed char*)(ws + ((size_t)106 << 20));
    float2* CTAB = (float2*)(ws + ((size_t)229 << 20));
    float* Hb = Qb;
    float* out = (float*)d_out;

    const dim3 blk(256);
    const int gxH = R_ / 128;                 // 16 row blocks
    const int nwgH = gxH * (H_ / 128);        // 512
    const int nwgI = gxH * (I_ / 128);        // 1376
    const dim3 gpH(H_ / 64, H_ / 128);        // pack grids: (nk, N/128)
    const dim3 gpI(H_ / 64, I_ / 128);
    const dim3 gpD(I_ / 64, H_ / 128);

    ropetab_k<<<256, blk, 0, stream>>>(CTAB);
    rmsnorm_quant_k<<<R_, blk, 0, stream>>>(hidden, ln1, HQ8);

    packW_k<<<gpH, blk, 0, stream>>>(Wq, WPa, H_);
    gemm_i8t<<<nwgH, blk, 0, stream>>>(HQ8, WPa, sq, bq, nullptr, Qb, H_, H_, gxH);
    packW_k<<<gpH, blk, 0, stream>>>(Wk, WPb, H_);
    packW_k<<<gpH, blk, 0, stream>>>(Wv, WPa, H_);
    // fused K+V projection: K fp32 -> Kb, V bf16 -> Vbf (shared-A dual GEMM)
    gemm_dual<1><<<nwgH, blk, 0, stream>>>(HQ8, WPb, WPa, sk, bk, sv, bv,
                                           nullptr, nullptr, Kb, Vbf, H_, H_, gxH);

    rope_k<<<R_, blk, 0, stream>>>(Qb, Kb, Kbf, CTAB);
    attn_mfma_k<<<B_ * NH_ * (S_ / 64), blk, 0, stream>>>(Qb, Kbf, Vbf, HQ8, o_sc);

    packW_k<<<gpH, blk, 0, stream>>>(Wo, WPb, H_);
    gemm_i8t<<<nwgH, blk, 0, stream>>>(HQ8, WPb, so, bo, hidden, Hb, H_, H_, gxH);

    rmsnorm_quant_k<<<R_, blk, 0, stream>>>(Hb, ln2, HQ8);

    packW_k<<<gpI, blk, 0, stream>>>(Wg, WPa, H_);
    packW_k<<<gpI, blk, 0, stream>>>(Wu, WPu, H_);
    gemm_dual<0><<<nwgI, blk, 0, stream>>>(HQ8, WPa, WPu, sg, bg, su, bu,
                                           d_sc, AQ8, nullptr, nullptr, I_, H_, gxH);
    packW_k<<<gpD, blk, 0, stream>>>(Wd, WPd, I_);
    gemm_i8t<<<nwgH, blk, 0, stream>>>(AQ8, WPd, sd, bd, Hb, out, H_, I_, gxH);
}

// Round 19
// 898.341 us; speedup vs baseline: 1.0290x; 1.0290x over previous
//
#include <hip/hip_runtime.h>
#include <math.h>

#define B_  2
#define S_  1024
#define H_  4096
#define NH_ 32
#define HD_ 128
#define I_  11008
#define R_  2048   // B*S tokens

typedef __attribute__((ext_vector_type(4))) int i32x4;
typedef __attribute__((ext_vector_type(4))) float f32x4;
typedef __attribute__((ext_vector_type(8))) short bf16x8;

// Tiled int8 layout (v1, validated): for matrix [Rows][K], nk = K/64;
// tile (rb, kt) is 8192 B at ((rb*nk + kt)<<13), internally
// [kgrp 0..3][row 0..127][16B]  (kgrp = (k%64)/16).
//
// r14 LESSON: kernels with hand-counted s_waitcnt vmcnt(N) must never spill —
// scratch buffer ops count toward vmcnt. Keep launch_bounds at the no-spill
// occupancy ((256,2) for the dual-acc GEMMs; 3-acc QKV would spill — don't).
// r7 LESSON: global_load_lds global src is PER-LANE; LDS dest is wave-uniform.
// r18: RoPE is folded into the Q-GEMM / KV-GEMM epilogues via a post-loop LDS
// exchange (after the final barrier -> no interaction with counted vmcnt).

// ---------------------------------------------------------------------------
__device__ __forceinline__ void gload_lds16(const void* g, void* l) {
    __builtin_amdgcn_global_load_lds(
        (const __attribute__((address_space(1))) unsigned int*)g,
        (__attribute__((address_space(3))) unsigned int*)l, 16, 0, 0);
}

__device__ __forceinline__ unsigned short f2bf(float f) {
    unsigned int u = __float_as_uint(f);
    u += 0x7fffu + ((u >> 16) & 1u);   // RNE
    return (unsigned short)(u >> 16);
}

// ---------------------------------------------------------------------------
// Pack one W (int32 [N][K]) into tiled-i8. Grid: (K/64, N/128).
__global__ __launch_bounds__(256)
void packW_k(const int* __restrict__ W, signed char* __restrict__ out, const int K)
{
    const int kt = blockIdx.x, cb = blockIdx.y, nk = gridDim.x;
    const int t = threadIdx.x;
    int* otile = (int*)(out + ((long)(cb * nk + kt) << 13));
#pragma unroll
    for (int i = 0; i < 8; ++i) {
        const int o = i * 256 + t;                 // int32 index in tile
        const int g = o >> 9, r = (o >> 2) & 127, jj = o & 3;
        const int4 w4 = *(const int4*)(W + (long)(cb * 128 + r) * K + kt * 64 + g * 16 + jj * 4);
        otile[o] = (w4.x & 255) | ((w4.y & 255) << 8) | ((w4.z & 255) << 16) | (w4.w << 24);
    }
}

// ---------------------------------------------------------------------------
// RoPE trig table: ctab[s*64+i] = (cos, sin) of s * 10000^(-2i/128).
__global__ __launch_bounds__(256)
void ropetab_k(float2* __restrict__ ctab)
{
    const int idx = blockIdx.x * 256 + threadIdx.x;   // 65536 entries
    const int s = idx >> 6, i = idx & 63;
    const float inv = powf(10000.f, -(float)(2 * i) * (1.f / 128.f));
    const float f = (float)s * inv;
    float sn, c;
    sincosf(f, &sn, &c);
    ctab[idx] = make_float2(c, sn);
}

// ---------------------------------------------------------------------------
// RMSNorm + int8 quant (scale folded into w). Output in tiled-i8 (nk=64).
__global__ __launch_bounds__(256)
void rmsnorm_quant_k(const float* __restrict__ x, const float* __restrict__ w,
                     signed char* __restrict__ out)
{
    __shared__ float red[4];
    const int tid = threadIdx.x;
    const long row = blockIdx.x;
    const float4* xr = (const float4*)(x + row * H_);
    float4 xv[4];
    float ss = 0.f;
#pragma unroll
    for (int i = 0; i < 4; ++i) {
        xv[i] = xr[tid + i * 256];
        ss += xv[i].x * xv[i].x + xv[i].y * xv[i].y
            + xv[i].z * xv[i].z + xv[i].w * xv[i].w;
    }
#pragma unroll
    for (int off = 32; off; off >>= 1) ss += __shfl_xor(ss, off);
    if ((tid & 63) == 0) red[tid >> 6] = ss;
    __syncthreads();
    const float tot = red[0] + red[1] + red[2] + red[3];
    const float sc = 1.f / sqrtf(tot * (1.f / (float)H_) + 1e-6f);
    const float4* wr = (const float4*)w;
    int* ob = (int*)out;
    const long rb = row >> 7;
    const int rr = (int)(row & 127);
#pragma unroll
    for (int i = 0; i < 4; ++i) {
        const float4 wv = wr[tid + i * 256];
        const int b0 = (int)fminf(fmaxf(rintf(xv[i].x * sc * wv.x), -128.f), 127.f);
        const int b1 = (int)fminf(fmaxf(rintf(xv[i].y * sc * wv.y), -128.f), 127.f);
        const int b2 = (int)fminf(fmaxf(rintf(xv[i].z * sc * wv.z), -128.f), 127.f);
        const int b3 = (int)fminf(fmaxf(rintf(xv[i].w * sc * wv.w), -128.f), 127.f);
        const int packed = (b0 & 255) | ((b1 & 255) << 8) | ((b2 & 255) << 16) | (b3 << 24);
        const int j4 = tid + i * 256;              // int32 group within row
        const long a32 = ((rb * 64 + (j4 >> 4)) << 11) + (((j4 >> 2) & 3) << 9)
                       + (rr << 2) + (j4 & 3);
        ob[a32] = packed;
    }
}

// ---------------------------------------------------------------------------
// int8 GEMM (round-8 validated): BK=128 double-step, depth-2 ring, counted
// vmcnt(8), 64KB LDS -> 2 blocks/CU. Wave-out 64x64 (acc[4][4]).
// MODE 0: C fp32 = acc*s + bias (+residual).
// MODE 1: Q projection with fused RoPE (post-loop LDS exchange) -> C fp32.
template<int MODE>
__global__ __launch_bounds__(256, 2)
void gemm_i8t(const signed char* __restrict__ A8, const signed char* __restrict__ W8,
              const float* __restrict__ scale_ptr, const float* __restrict__ bias,
              const float* __restrict__ residual, float* __restrict__ C,
              const float2* __restrict__ ctab,
              const int N, const int K, const int gx)
{
    __shared__ __align__(16) signed char lsA[2][16384];
    __shared__ __align__(16) signed char lsB[2][16384];

    int bid = blockIdx.x;
    {   // bijective XCD chunked remap (m204)
        const int nwg = gridDim.x;
        const int q = nwg >> 3, r = nwg & 7;
        const int xcd = bid & 7, idx = bid >> 3;
        bid = (xcd < r) ? (xcd * (q + 1) + idx)
                        : (r * (q + 1) + (xcd - r) * q + idx);
    }
    const int bx = bid % gx, by = bid / gx;

    const int tid  = threadIdx.x;
    const int lane = tid & 63, wid = tid >> 6;
    const int bm = bx << 7, bn = by << 7;
    const int wm = (wid >> 1) << 6, wn = (wid & 1) << 6;

    i32x4 acc[4][4];
#pragma unroll
    for (int m = 0; m < 4; ++m)
#pragma unroll
        for (int n = 0; n < 4; ++n) acc[m][n] = (i32x4){0, 0, 0, 0};

    const int nk  = K >> 6;
    const int nk2 = K >> 7;
    const signed char* abase = A8 + ((long)bx * nk << 13);
    const signed char* bbase = W8 + ((long)by * nk << 13);
    const int sgg = wid * 4096 + lane * 16;        // GLOBAL src: per-lane
    const int sgl = wid * 4096;                    // LDS dest: wave-uniform

#pragma unroll
    for (int c = 0; c < 4; ++c) {
        gload_lds16(abase + sgg + c * 1024, lsA[0] + sgl + c * 1024);
        gload_lds16(bbase + sgg + c * 1024, lsB[0] + sgl + c * 1024);
    }

    for (int kt = 0; kt < nk2; ++kt) {
        const int cur = kt & 1, nxt = cur ^ 1;
        if (kt + 1 < nk2) {
            const signed char* at = abase + ((long)(kt + 1) << 14);
            const signed char* bt = bbase + ((long)(kt + 1) << 14);
#pragma unroll
            for (int c = 0; c < 4; ++c) {
                gload_lds16(at + sgg + c * 1024, lsA[nxt] + sgl + c * 1024);
                gload_lds16(bt + sgg + c * 1024, lsB[nxt] + sgl + c * 1024);
            }
            asm volatile("s_waitcnt vmcnt(8)" ::: "memory");
        } else {
            asm volatile("s_waitcnt vmcnt(0)" ::: "memory");
        }
        __builtin_amdgcn_s_barrier();

        const int kg = (lane >> 4) * 2048, fr = (lane & 15) * 16;
#pragma unroll
        for (int s = 0; s < 2; ++s) {
            const int off = s * 8192;
            i32x4 af[4], bf[4];
#pragma unroll
            for (int m = 0; m < 4; ++m)
                af[m] = *(const i32x4*)(lsA[cur] + off + kg + wm * 16 + m * 256 + fr);
#pragma unroll
            for (int n = 0; n < 4; ++n)
                bf[n] = *(const i32x4*)(lsB[cur] + off + kg + wn * 16 + n * 256 + fr);
            __builtin_amdgcn_s_setprio(1);
#pragma unroll
            for (int m = 0; m < 4; ++m)
#pragma unroll
                for (int n = 0; n < 4; ++n)
                    acc[m][n] = __builtin_amdgcn_mfma_i32_16x16x64_i8(af[m], bf[n], acc[m][n], 0, 0, 0);
            __builtin_amdgcn_s_setprio(0);
        }
        __builtin_amdgcn_s_barrier();
    }

    const float s = *scale_ptr;
    const int rq = (lane >> 4) * 4, fc = lane & 15;
    if (MODE == 0) {
#pragma unroll
        for (int m = 0; m < 4; ++m) {
#pragma unroll
            for (int n = 0; n < 4; ++n) {
                const int col = bn + wn + n * 16 + fc;
                const float bcol = bias[col];
#pragma unroll
                for (int r = 0; r < 4; ++r) {
                    const int row = bm + wm + m * 16 + rq + r;
                    float v = (float)acc[m][n][r] * s + bcol;
                    if (residual) v += residual[(long)row * N + col];
                    C[(long)row * N + col] = v;
                }
            }
        }
    } else {
        // MODE 1: fused RoPE. Side-B (wn=64) stores its values to LDS scratch
        // (lsA: contiguous 32KB = [128 rows][64 cols] fp32), then side-A
        // computes both roped halves.
        float* scp = (float*)lsA;
        if (wn) {
#pragma unroll
            for (int m = 0; m < 4; ++m) {
#pragma unroll
                for (int n = 0; n < 4; ++n) {
                    const int colL = n * 16 + fc;
                    const float bcol = bias[bn + 64 + colL];
#pragma unroll
                    for (int r = 0; r < 4; ++r) {
                        const int rowL = wm + m * 16 + rq + r;
                        scp[rowL * 64 + colL] = (float)acc[m][n][r] * s + bcol;
                    }
                }
            }
        }
        __syncthreads();
        if (!wn) {
#pragma unroll
            for (int m = 0; m < 4; ++m) {
#pragma unroll
                for (int n = 0; n < 4; ++n) {
                    const int i = n * 16 + fc;
                    const float bcol = bias[bn + i];
#pragma unroll
                    for (int r = 0; r < 4; ++r) {
                        const int rowL = wm + m * 16 + rq + r;
                        const int grow = bm + rowL;
                        const float q0 = (float)acc[m][n][r] * s + bcol;
                        const float q1 = scp[rowL * 64 + i];
                        const float2 cs = ctab[((grow & (S_ - 1)) << 6) + i];
                        C[(long)grow * N + bn + i]      = q0 * cs.x - q1 * cs.y;
                        C[(long)grow * N + bn + i + 64] = q1 * cs.x + q0 * cs.y;
                    }
                }
            }
        }
    }
}

// ---------------------------------------------------------------------------
// Dual-accumulator shared-A GEMM skeleton (gemm_gu pattern, r11 validated):
// 48KB LDS ring, counted vmcnt(6), (256,2) no-spill.
// EPI 0 (gemm_gu): silu(g)*u -> quant -> AQ8 tiled-i8.
// EPI 1 (gemm_kv): K with fused RoPE -> Kbf bf16; V -> Vbf bf16.
template<int EPI>
__global__ __launch_bounds__(256, 2)
void gemm_dual(const signed char* __restrict__ A8, const signed char* __restrict__ G8,
               const signed char* __restrict__ U8,
               const float* __restrict__ s1_p, const float* __restrict__ b1,
               const float* __restrict__ s2_p, const float* __restrict__ b2,
               const float* __restrict__ qscale, signed char* __restrict__ out8,
               unsigned short* __restrict__ Kbf, unsigned short* __restrict__ Cbf,
               const float2* __restrict__ ctab,
               const int N, const int K, const int gx)
{
    __shared__ __align__(16) signed char lsA[2][8192];
    __shared__ __align__(16) signed char lsG[2][8192];
    __shared__ __align__(16) signed char lsU[2][8192];

    int bid = blockIdx.x;
    {   // bijective XCD chunked remap
        const int nwg = gridDim.x;
        const int q = nwg >> 3, r = nwg & 7;
        const int xcd = bid & 7, idx = bid >> 3;
        bid = (xcd < r) ? (xcd * (q + 1) + idx)
                        : (r * (q + 1) + (xcd - r) * q + idx);
    }
    const int bx = bid % gx, by = bid / gx;
    const int tid = threadIdx.x, lane = tid & 63, wid = tid >> 6;
    const int bm = bx << 7, bn = by << 7;
    const int wm = (wid >> 1) << 6, wn = (wid & 1) << 6;

    i32x4 ag[4][4], au[4][4];
#pragma unroll
    for (int m = 0; m < 4; ++m)
#pragma unroll
        for (int n = 0; n < 4; ++n) {
            ag[m][n] = (i32x4){0, 0, 0, 0};
            au[m][n] = (i32x4){0, 0, 0, 0};
        }

    const int nk = K >> 6;
    const signed char* abase = A8 + ((long)bx * nk << 13);
    const signed char* gbase = G8 + ((long)by * nk << 13);
    const signed char* ubase = U8 + ((long)by * nk << 13);
    const int sgg = wid * 2048 + lane * 16;        // GLOBAL src: per-lane
    const int sgl = wid * 2048;                    // LDS dest: wave-uniform

#pragma unroll
    for (int c = 0; c < 2; ++c) {
        gload_lds16(abase + sgg + c * 1024, lsA[0] + sgl + c * 1024);
        gload_lds16(gbase + sgg + c * 1024, lsG[0] + sgl + c * 1024);
        gload_lds16(ubase + sgg + c * 1024, lsU[0] + sgl + c * 1024);
    }

    for (int kt = 0; kt < nk; ++kt) {
        const int cur = kt & 1, nxt = cur ^ 1;
        if (kt + 1 < nk) {
            const signed char* at = abase + ((long)(kt + 1) << 13);
            const signed char* gt = gbase + ((long)(kt + 1) << 13);
            const signed char* ut = ubase + ((long)(kt + 1) << 13);
#pragma unroll
            for (int c = 0; c < 2; ++c) {
                gload_lds16(at + sgg + c * 1024, lsA[nxt] + sgl + c * 1024);
                gload_lds16(gt + sgg + c * 1024, lsG[nxt] + sgl + c * 1024);
                gload_lds16(ut + sgg + c * 1024, lsU[nxt] + sgl + c * 1024);
            }
            asm volatile("s_waitcnt vmcnt(6)" ::: "memory");   // drain step kt's 6
        } else {
            asm volatile("s_waitcnt vmcnt(0)" ::: "memory");
        }
        __builtin_amdgcn_s_barrier();              // step kt visible

        const int kg = (lane >> 4) * 2048, fr = (lane & 15) * 16;
        i32x4 af[4], gf[4], uf[4];
#pragma unroll
        for (int m = 0; m < 4; ++m)
            af[m] = *(const i32x4*)(lsA[cur] + kg + wm * 16 + m * 256 + fr);
#pragma unroll
        for (int n = 0; n < 4; ++n) {
            gf[n] = *(const i32x4*)(lsG[cur] + kg + wn * 16 + n * 256 + fr);
            uf[n] = *(const i32x4*)(lsU[cur] + kg + wn * 16 + n * 256 + fr);
        }
        __builtin_amdgcn_s_setprio(1);
#pragma unroll
        for (int m = 0; m < 4; ++m)
#pragma unroll
            for (int n = 0; n < 4; ++n) {
                ag[m][n] = __builtin_amdgcn_mfma_i32_16x16x64_i8(af[m], gf[n], ag[m][n], 0, 0, 0);
                au[m][n] = __builtin_amdgcn_mfma_i32_16x16x64_i8(af[m], uf[n], au[m][n], 0, 0, 0);
            }
        __builtin_amdgcn_s_setprio(0);
        __builtin_amdgcn_s_barrier();              // buf[cur] free
    }

    const float s1 = *s1_p, s2 = *s2_p;
    const int rq = (lane >> 4) * 4, fc = lane & 15;
    if (EPI == 0) {
        const float dinv = 1.f / qscale[0];
        const int nko = N >> 6;
#pragma unroll
        for (int m = 0; m < 4; ++m) {
#pragma unroll
            for (int n = 0; n < 4; ++n) {
                const int col = bn + wn + n * 16 + fc;
                const float bgc = b1[col], buc = b2[col];
                const int ktc = col >> 6, kgc = (col >> 4) & 3, jc = col & 15;
#pragma unroll
                for (int r = 0; r < 4; ++r) {
                    const int row = bm + wm + m * 16 + rq + r;
                    const float g = (float)ag[m][n][r] * s1 + bgc;
                    const float u = (float)au[m][n][r] * s2 + buc;
                    const float a = g / (1.f + __expf(-g)) * u;
                    const float qv = fminf(fmaxf(rintf(a * dinv), -128.f), 127.f);
                    const long addr = (((long)(row >> 7) * nko + ktc) << 13)
                                    + (kgc << 11) + ((row & 127) << 4) + jc;
                    out8[addr] = (signed char)(int)qv;
                }
            }
        }
    } else {
        // V: all waves write bf16 directly.
#pragma unroll
        for (int m = 0; m < 4; ++m) {
#pragma unroll
            for (int n = 0; n < 4; ++n) {
                const int col = bn + wn + n * 16 + fc;
                const float bvc = b2[col];
#pragma unroll
                for (int r = 0; r < 4; ++r) {
                    const int row = bm + wm + m * 16 + rq + r;
                    Cbf[(long)row * N + col] = f2bf((float)au[m][n][r] * s2 + bvc);
                }
            }
        }
        // K with fused RoPE: side-B stores to LDS scratch, side-A writes both
        // roped halves. Scratch: lsA (rows 0..63) + lsG (rows 64..127).
        float* sc0 = (float*)lsA;
        float* sc1 = (float*)lsG;
        if (wn) {
#pragma unroll
            for (int m = 0; m < 4; ++m) {
#pragma unroll
                for (int n = 0; n < 4; ++n) {
                    const int colL = n * 16 + fc;
                    const float bkc = b1[bn + 64 + colL];
#pragma unroll
                    for (int r = 0; r < 4; ++r) {
                        const int rowL = wm + m * 16 + rq + r;
                        float* scp = (rowL < 64) ? sc0 : sc1;
                        scp[(rowL & 63) * 64 + colL] = (float)ag[m][n][r] * s1 + bkc;
                    }
                }
            }
        }
        __syncthreads();
        if (!wn) {
#pragma unroll
            for (int m = 0; m < 4; ++m) {
#pragma unroll
                for (int n = 0; n < 4; ++n) {
                    const int i = n * 16 + fc;
                    const float bkc = b1[bn + i];
#pragma unroll
                    for (int r = 0; r < 4; ++r) {
                        const int rowL = wm + m * 16 + rq + r;
                        const int grow = bm + rowL;
                        const float k0 = (float)ag[m][n][r] * s1 + bkc;
                        const float* scp = (rowL < 64) ? sc0 : sc1;
                        const float k1 = scp[(rowL & 63) * 64 + i];
                        const float2 cs = ctab[((grow & (S_ - 1)) << 6) + i];
                        Kbf[(long)grow * N + bn + i]      = f2bf(k0 * cs.x - k1 * cs.y);
                        Kbf[(long)grow * N + bn + i + 64] = f2bf(k1 * cs.x + k0 * cs.y);
                    }
                }
            }
        }
    }
}

// ---------------------------------------------------------------------------
// Flash attention, bf16 MFMA; Q arrives roped fp32, K/V pre-converted bf16.
__global__ __launch_bounds__(256, 3)
void attn_mfma_k(const float* __restrict__ q, const unsigned short* __restrict__ kbf,
                 const unsigned short* __restrict__ vbf, signed char* __restrict__ out8,
                 const float* __restrict__ osc)
{
    __shared__ __align__(16) char lsK[8192];        // [32 krow][128 d] bf16, XOR swizzle
    __shared__ __align__(16) char lsV[10240];       // V^T [128 d][40 pitch] bf16
    __shared__ __align__(16) char lsP[4][1024];     // per-wave P [16][32] bf16, XOR swizzle

    const int tid = threadIdx.x, lane = tid & 63, wid = tid >> 6;
    const int bid = blockIdx.x;
    const int qt = 15 - (bid >> 6);                 // reversed: long blocks first
    const int bh = bid & 63;
    const int b = bh >> 5, h = bh & 31;
    const int q0 = qt * 64;
    const int qw = q0 + wid * 16;                   // this wave's first q row

    const float* qbase = q + (long)(b * S_) * H_ + (long)h * HD_;
    const unsigned short* kbase = kbf + (long)(b * S_) * H_ + (long)h * HD_;
    const unsigned short* vbase = vbf + (long)(b * S_) * H_ + (long)h * HD_;

    const int frow = lane & 15, fgrp = lane >> 4;
    const float sc = 0.08838834764831845f;          // 1/sqrt(128), folded into Q

    bf16x8 qf[4];
    {
        const float* qr = qbase + (long)(qw + frow) * H_;
#pragma unroll
        for (int c = 0; c < 4; ++c) {
            const float4 a = *(const float4*)(qr + c * 32 + fgrp * 8);
            const float4 bq = *(const float4*)(qr + c * 32 + fgrp * 8 + 4);
            bf16x8 t;
            t[0] = (short)f2bf(a.x * sc);  t[1] = (short)f2bf(a.y * sc);
            t[2] = (short)f2bf(a.z * sc);  t[3] = (short)f2bf(a.w * sc);
            t[4] = (short)f2bf(bq.x * sc); t[5] = (short)f2bf(bq.y * sc);
            t[6] = (short)f2bf(bq.z * sc); t[7] = (short)f2bf(bq.w * sc);
            qf[c] = t;
        }
    }

    f32x4 oacc[8];
#pragma unroll
    for (int n2 = 0; n2 < 8; ++n2) oacc[n2] = (f32x4){0.f, 0.f, 0.f, 0.f};
    float mr[4] = {-1e30f, -1e30f, -1e30f, -1e30f};
    float lr[4] = {0.f, 0.f, 0.f, 0.f};

    const int nt = (q0 >> 5) + 2;
    for (int kt = 0; kt < nt; ++kt) {
        if (kt) __syncthreads();
        {
            const unsigned short* kg = kbase + (long)(kt * 32) * H_;
            const unsigned short* vg = vbase + (long)(kt * 32) * H_;
#pragma unroll
            for (int i = 0; i < 2; ++i) {
                const int lin = i * 256 + tid;      // 512 units of 8 bf16
                const int kr = lin >> 4;            // 0..31
                const int d8 = (lin & 15) * 8;      // 0..120
                const bf16x8 kv = *(const bf16x8*)(kg + (long)kr * H_ + d8);
                *(bf16x8*)(lsK + kr * 256 + ((d8 * 2) ^ ((kr & 7) << 4))) = kv;
                const bf16x8 vv = *(const bf16x8*)(vg + (long)kr * H_ + d8);
#pragma unroll
                for (int e = 0; e < 8; ++e)
                    *(unsigned short*)(lsV + (d8 + e) * 80 + kr * 2) = (unsigned short)vv[e];
            }
        }
        __syncthreads();

        if (kt * 32 <= qw + 15) {
            f32x4 s0 = (f32x4){0.f, 0.f, 0.f, 0.f};
            f32x4 s1 = (f32x4){0.f, 0.f, 0.f, 0.f};
            const int swz = (frow & 7) << 4;
#pragma unroll
            for (int c = 0; c < 4; ++c) {
                const int dby = c * 64 + fgrp * 16;
                const bf16x8 kfA = *(const bf16x8*)(lsK + frow * 256 + (dby ^ swz));
                const bf16x8 kfB = *(const bf16x8*)(lsK + (frow + 16) * 256 + (dby ^ swz));
                s0 = __builtin_amdgcn_mfma_f32_16x16x32_bf16(qf[c], kfA, s0, 0, 0, 0);
                s1 = __builtin_amdgcn_mfma_f32_16x16x32_bf16(qf[c], kfB, s1, 0, 0, 0);
            }

            const int colg0 = kt * 32 + frow;
            float cf[4];
#pragma unroll
            for (int r = 0; r < 4; ++r) {
                const int rowg = qw + fgrp * 4 + r;
                const float a0 = (colg0 <= rowg) ? s0[r] : -1e30f;
                const float a1 = (colg0 + 16 <= rowg) ? s1[r] : -1e30f;
                float mx = fmaxf(a0, a1);
#pragma unroll
                for (int off2 = 1; off2 < 16; off2 <<= 1) mx = fmaxf(mx, __shfl_xor(mx, off2));
                const float mnew = fmaxf(mr[r], mx);
                cf[r] = __expf(mr[r] - mnew);
                mr[r] = mnew;
                const float p0 = __expf(a0 - mnew);
                const float p1 = __expf(a1 - mnew);
                float sm = p0 + p1;
#pragma unroll
                for (int off2 = 1; off2 < 16; off2 <<= 1) sm += __shfl_xor(sm, off2);
                lr[r] = lr[r] * cf[r] + sm;
                const int row = fgrp * 4 + r;
                const int psw = (row & 3) << 4;
                *(unsigned short*)(lsP[wid] + row * 64 + ((frow * 2) ^ psw)) = f2bf(p0);
                *(unsigned short*)(lsP[wid] + row * 64 + (((16 + frow) * 2) ^ psw)) = f2bf(p1);
            }
#pragma unroll
            for (int n2 = 0; n2 < 8; ++n2) {
#pragma unroll
                for (int r = 0; r < 4; ++r) oacc[n2][r] *= cf[r];
            }
            const bf16x8 pf = *(const bf16x8*)(lsP[wid] + frow * 64 + ((fgrp * 16) ^ ((frow & 3) << 4)));
#pragma unroll
            for (int n2 = 0; n2 < 8; ++n2) {
                const bf16x8 vf = *(const bf16x8*)(lsV + (n2 * 16 + frow) * 80 + fgrp * 16);
                oacc[n2] = __builtin_amdgcn_mfma_f32_16x16x32_bf16(pf, vf, oacc[n2], 0, 0, 0);
            }
        }
    }

    // epilogue: o = oacc/l, q8 = clip(rint(o/osc)) -> tiled-i8 (nk = 64)
    const float oinv = 1.f / osc[0];
    float inv[4];
#pragma unroll
    for (int r = 0; r < 4; ++r) inv[r] = 1.f / lr[r];
#pragma unroll
    for (int n2 = 0; n2 < 8; ++n2) {
        const int kk = h * 128 + n2 * 16 + frow;
        const int ktc = kk >> 6, kgc = (kk >> 4) & 3, jc = kk & 15;
#pragma unroll
        for (int r = 0; r < 4; ++r) {
            const int rowt = b * S_ + qw + fgrp * 4 + r;
            const float ov = oacc[n2][r] * inv[r];
            const float qv = fminf(fmaxf(rintf(ov * oinv), -128.f), 127.f);
            const long addr = (((long)(rowt >> 7) * 64 + ktc) << 13)
                            + (kgc << 11) + ((rowt & 127) << 4) + jc;
            out8[addr] = (signed char)(int)qv;
        }
    }
}

// ---------------------------------------------------------------------------
extern "C" void kernel_launch(void* const* d_in, const int* in_sizes, int n_in,
                              void* d_out, int out_size, void* d_ws, size_t ws_size,
                              hipStream_t stream)
{
    const float* hidden = (const float*)d_in[0];
    const float* ln1 = (const float*)d_in[1];
    const float* ln2 = (const float*)d_in[2];
    const int* Wq = (const int*)d_in[3];
    const int* Wk = (const int*)d_in[4];
    const int* Wv = (const int*)d_in[5];
    const int* Wo = (const int*)d_in[6];
    const int* Wg = (const int*)d_in[7];
    const int* Wu = (const int*)d_in[8];
    const int* Wd = (const int*)d_in[9];
    const float* bq = (const float*)d_in[10];
    const float* bk = (const float*)d_in[11];
    const float* bv = (const float*)d_in[12];
    const float* bo = (const float*)d_in[13];
    const float* bg = (const float*)d_in[14];
    const float* bu = (const float*)d_in[15];
    const float* bd = (const float*)d_in[16];
    const float* sq = (const float*)d_in[17];
    const float* sk = (const float*)d_in[18];
    const float* sv = (const float*)d_in[19];
    const float* so = (const float*)d_in[20];
    const float* sg = (const float*)d_in[21];
    const float* su = (const float*)d_in[22];
    const float* sd = (const float*)d_in[23];
    const float* o_sc = (const float*)d_in[24];
    const float* d_sc = (const float*)d_in[25];

    // workspace layout (MiB offsets, peak 230 MiB):
    //  [0,8)     HQ8 tiled i8 (hq / oq / hq2, sequential reuse)
    //  [8,30)    AQ8 tiled i8 (2048 x 11008)
    //  [30,74)   WPa: Wq -> Wv -> Wg packed (44 MiB)
    //  [74,106)  Qb fp32 (roped) -> (post-attn) Hb
    //  [138,154) Vbf bf16 ; [154,170) Kbf bf16 (roped)  (dead after attn)
    //  [170,186) WPb: Wk -> Wo packed (16 MiB)
    //  [186,229) WPu: Wu packed (43 MiB)
    //  [106,149) WPd: Wd packed (43 MiB, over free region + dead Vbf, after attn)
    //  [229,229.5) ctab: rope trig table (512 KB)
    char* ws = (char*)d_ws;
    signed char* HQ8 = (signed char*)ws;
    signed char* AQ8 = (signed char*)(ws + ((size_t)8 << 20));
    signed char* WPa = (signed char*)(ws + ((size_t)30 << 20));
    float* Qb = (float*)(ws + ((size_t)74 << 20));
    unsigned short* Vbf = (unsigned short*)(ws + ((size_t)138 << 20));
    unsigned short* Kbf = (unsigned short*)(ws + ((size_t)154 << 20));
    signed char* WPb = (signed char*)(ws + ((size_t)170 << 20));
    signed char* WPu = (signed char*)(ws + ((size_t)186 << 20));
    signed char* WPd = (signed char*)(ws + ((size_t)106 << 20));
    float2* CTAB = (float2*)(ws + ((size_t)229 << 20));
    float* Hb = Qb;
    float* out = (float*)d_out;

    const dim3 blk(256);
    const int gxH = R_ / 128;                 // 16 row blocks
    const int nwgH = gxH * (H_ / 128);        // 512
    const int nwgI = gxH * (I_ / 128);        // 1376
    const dim3 gpH(H_ / 64, H_ / 128);        // pack grids: (nk, N/128)
    const dim3 gpI(H_ / 64, I_ / 128);
    const dim3 gpD(I_ / 64, H_ / 128);

    ropetab_k<<<256, blk, 0, stream>>>(CTAB);
    rmsnorm_quant_k<<<R_, blk, 0, stream>>>(hidden, ln1, HQ8);

    packW_k<<<gpH, blk, 0, stream>>>(Wq, WPa, H_);
    // Q projection with fused RoPE -> Qb (fp32, roped)
    gemm_i8t<1><<<nwgH, blk, 0, stream>>>(HQ8, WPa, sq, bq, nullptr, Qb, CTAB, H_, H_, gxH);
    packW_k<<<gpH, blk, 0, stream>>>(Wk, WPb, H_);
    packW_k<<<gpH, blk, 0, stream>>>(Wv, WPa, H_);
    // fused K+V projection: K roped bf16 -> Kbf, V bf16 -> Vbf
    gemm_dual<1><<<nwgH, blk, 0, stream>>>(HQ8, WPb, WPa, sk, bk, sv, bv,
                                           nullptr, nullptr, Kbf, Vbf, CTAB, H_, H_, gxH);

    attn_mfma_k<<<B_ * NH_ * (S_ / 64), blk, 0, stream>>>(Qb, Kbf, Vbf, HQ8, o_sc);

    packW_k<<<gpH, blk, 0, stream>>>(Wo, WPb, H_);
    gemm_i8t<0><<<nwgH, blk, 0, stream>>>(HQ8, WPb, so, bo, hidden, Hb, nullptr, H_, H_, gxH);

    rmsnorm_quant_k<<<R_, blk, 0, stream>>>(Hb, ln2, HQ8);

    packW_k<<<gpI, blk, 0, stream>>>(Wg, WPa, H_);
    packW_k<<<gpI, blk, 0, stream>>>(Wu, WPu, H_);
    gemm_dual<0><<<nwgI, blk, 0, stream>>>(HQ8, WPa, WPu, sg, bg, su, bu,
                                           d_sc, AQ8, nullptr, nullptr, nullptr, I_, H_, gxH);
    packW_k<<<gpD, blk, 0, stream>>>(Wd, WPd, I_);
    gemm_i8t<0><<<nwgH, blk, 0, stream>>>(AQ8, WPd, sd, bd, Hb, out, nullptr, H_, I_, gxH);
}